// Round 4
// baseline (618.117 us; speedup 1.0000x reference)
//
#include <hip/hip_runtime.h>
#include <stdint.h>

#define TT 128
#define BSZ 512
#define HID 512
#define KDIM 512
#define BH (BSZ*HID)   // 262144 neurons

// ---------------- fp32 tiled GEMM: C[m][n] = sum_k A[m][k] * W[n][k] + bias[n] --------
// v5: WAVE-UNIFORM A. v1-v4 all hit the same wall: with A and B both streamed per-lane
// from LDS, VALU busy-time pinned at 272-297us (floor 218us) with 128 acc VGPRs parked
// in AGPRs (accvgpr shuffles) and ~160us idle from LDS-pipe contention at ~2 waves/SIMD.
// Also measured: v_pk_fma_f32 on CDNA4 is rate-neutral per FLOP (R3: VALUBusy 70->63%
// but time 403->431; 157.3TF spec = scalar rate).
// Fix: each wave owns 8 whole m-rows x 256 n-cols -> A operands are WAVE-UNIFORM:
//  - acc = 8x4 = 32 VGPRs (no AGPR parking possible)
//  - A loaded via uniform addresses (readfirstlane-provable) -> s_load / broadcast;
//    v_fma_f32 takes the A value as its one allowed SGPR source. A never touches LDS.
//  - B is the only LDS user: dbl-buffered [k][n] tile, 33KB -> 4 blocks/CU,
//    4 waves/SIMD (was ~2). LDS traffic 12.9GB -> 8.6GB (0.5 B/lane-fma), subcritical.
// Block: 256 thr = 4 waves; tile 32(m) x 256(n); BK=16; grid (HID/256, M/32).
// NUMERICS CONTRACT (bit-exact vs np ref, absmax 0.0): per output element the
// reduction is ONE sequential fp32 fma chain over k ascending, in one lane. Unchanged.
__global__ __launch_bounds__(256, 4) void gemm_f32(
    const float* __restrict__ A, const float* __restrict__ W,
    const float* __restrict__ bias, float* __restrict__ C) {
  __shared__ float Bs[2][16][260];   // [buf][k][n], +4/row bank shift (proven pattern)
  const int t    = threadIdx.x;
  const int m0   = blockIdx.y * 32;
  const int n0   = blockIdx.x * 256;
  const int lane = t & 63;
  // readfirstlane makes wave-uniformity explicit to the compiler: all A addressing
  // below is scalar, so loads from the const __restrict__ A select the scalar path.
  const int wid  = __builtin_amdgcn_readfirstlane(t >> 6);    // 0..3
  const int r0   = t >> 2;           // B staging row 0..63 (+64/128/192 replicas)
  const int kg   = t & 3;            // k float4 group within 16-wide k tile

  float acc[8][4];
  #pragma unroll
  for (int i = 0; i < 8; ++i)
    #pragma unroll
    for (int j = 0; j < 4; ++j) acc[i][j] = 0.f;

  const float* Wp = W + (size_t)(n0 + r0) * KDIM + kg * 4;
  const float* Aw = A + (size_t)(m0 + wid * 8) * KDIM;        // uniform base

  float4 w0 = *(const float4*)Wp;
  float4 w1 = *(const float4*)(Wp + (size_t)64  * KDIM);
  float4 w2 = *(const float4*)(Wp + (size_t)128 * KDIM);
  float4 w3 = *(const float4*)(Wp + (size_t)192 * KDIM);

  // stage B tile into buffer BUF (16 b32 scatter writes; 2-way bank alias only -> free)
  #define STAGE(BUF) do { \
    Bs[BUF][kg*4+0][r0]     = w0.x; Bs[BUF][kg*4+1][r0]     = w0.y; \
    Bs[BUF][kg*4+2][r0]     = w0.z; Bs[BUF][kg*4+3][r0]     = w0.w; \
    Bs[BUF][kg*4+0][r0+64]  = w1.x; Bs[BUF][kg*4+1][r0+64]  = w1.y; \
    Bs[BUF][kg*4+2][r0+64]  = w1.z; Bs[BUF][kg*4+3][r0+64]  = w1.w; \
    Bs[BUF][kg*4+0][r0+128] = w2.x; Bs[BUF][kg*4+1][r0+128] = w2.y; \
    Bs[BUF][kg*4+2][r0+128] = w2.z; Bs[BUF][kg*4+3][r0+128] = w2.w; \
    Bs[BUF][kg*4+0][r0+192] = w3.x; Bs[BUF][kg*4+1][r0+192] = w3.y; \
    Bs[BUF][kg*4+2][r0+192] = w3.z; Bs[BUF][kg*4+3][r0+192] = w3.w; \
  } while (0)

  STAGE(0);

  int cur = 0;
  for (int k0 = 0; k0 < KDIM; k0 += 16) {
    // Single barrier per tile (drains all mem ops): buf[cur] writes visible, and the
    // previous iteration's ds_reads of buf[cur^1] are complete -> restaging is safe.
    __syncthreads();
    const bool more = (k0 + 16 < KDIM);
    if (more) {   // vector prefetch of next B tile; latency hidden under fma block
      w0 = *(const float4*)(Wp + k0 + 16);
      w1 = *(const float4*)(Wp + (size_t)64  * KDIM + k0 + 16);
      w2 = *(const float4*)(Wp + (size_t)128 * KDIM + k0 + 16);
      w3 = *(const float4*)(Wp + (size_t)192 * KDIM + k0 + 16);
    }

    // 4 quads of k: per quad, load 8 uniform float4 A-chunks (scalar path), then
    // 4 kk steps x 8 rows x 4 cols of v_fma (A value = the one SGPR source).
    #pragma unroll
    for (int kq = 0; kq < 4; ++kq) {
      float4 aq[8];
      #pragma unroll
      for (int i = 0; i < 8; ++i)
        aq[i] = *(const float4*)(Aw + (size_t)i * KDIM + k0 + kq * 4);
      #pragma unroll
      for (int kk = 0; kk < 4; ++kk) {
        const float4 xb = *(const float4*)&Bs[cur][kq*4 + kk][lane*4]; // stride-1 16B/lane
        #pragma unroll
        for (int i = 0; i < 8; ++i) {
          const float ai = (kk == 0) ? aq[i].x : (kk == 1) ? aq[i].y
                         : (kk == 2) ? aq[i].z : aq[i].w;
          acc[i][0] = __builtin_fmaf(ai, xb.x, acc[i][0]);
          acc[i][1] = __builtin_fmaf(ai, xb.y, acc[i][1]);
          acc[i][2] = __builtin_fmaf(ai, xb.z, acc[i][2]);
          acc[i][3] = __builtin_fmaf(ai, xb.w, acc[i][3]);
        }
      }
    }

    if (more) {
      const int nb = cur ^ 1;
      STAGE(nb);      // overlaps other waves' compute; protected by next barrier
    }
    cur ^= 1;
  }
  #undef STAGE

  // epilogue: + bias (ref adds b once to xp — identical), coalesced float4 stores
  const float4 bv = *(const float4*)&bias[n0 + lane*4];
  #pragma unroll
  for (int i = 0; i < 8; ++i) {
    const float4 v = {acc[i][0] + bv.x, acc[i][1] + bv.y,
                      acc[i][2] + bv.z, acc[i][3] + bv.w};
    *(float4*)(C + (size_t)(m0 + wid*8 + i) * HID + n0 + lane*4) = v;
  }
}

// ---------------- LIF scan (bit-identical to np fp32 reference given xp) ----------------
__device__ __forceinline__ float lif_step(float y, float v[4], float av[4]) {
  float as3 = 0.f;
  #pragma unroll
  for (int l = 0; l < 4; ++l) {
    float vv = v[l];
    float accv = 0.f, accs = 0.f;
    #pragma unroll
    for (int k = 0; k < 4; ++k) {
      const float d = y - vv;                        // round(inp - v)
      vv = __builtin_fmaf(d, 0.5f, vv);              // round(v + d*0.5): d*0.5 exact
      const float spk = (vv >= 1.0f) ? 1.0f : 0.0f;  // v-1>=0 <=> v>=1 (exact)
      vv -= spk;                                     // soft reset
      accv += vv;
      accs += spk;
    }
    v[l] = vv;
    const float a = accv * 0.25f;                    // exact /4
    av[l] = a;
    y = a;                                           // next layer consumes avg_v
    as3 = accs;
  }
  return as3;
}

// One thread per neuron. xp loads are INDEPENDENT across t (precomputed array).
// 8-deep prefetch + nontemporal xp loads / out stores (each touched exactly once).
__global__ __launch_bounds__(256) void lif_scan(
    const float* __restrict__ xp, float* __restrict__ outp, float* __restrict__ vstate,
    int tc, int first, int last) {
  const int idx = blockIdx.x * 256 + threadIdx.x;
  float v[4];
  if (first) {
    #pragma unroll
    for (int l = 0; l < 4; ++l) v[l] = 0.f;
  } else {
    #pragma unroll
    for (int l = 0; l < 4; ++l) v[l] = vstate[(size_t)l * BH + idx];
  }
  float av[4] = {0.f, 0.f, 0.f, 0.f};
  const float* p = xp + idx;
  float* op = outp + idx;

  if ((tc & 7) == 0 && tc >= 16) {
    float curb[8];
    #pragma unroll
    for (int i = 0; i < 8; ++i) curb[i] = __builtin_nontemporal_load(&p[(size_t)i * BH]);
    for (int t = 0; t + 8 < tc; t += 8) {
      float nxtb[8];
      #pragma unroll
      for (int i = 0; i < 8; ++i)
        nxtb[i] = __builtin_nontemporal_load(&p[(size_t)(i + 8) * BH]);  // pre-compute
      #pragma unroll
      for (int i = 0; i < 8; ++i) {
        const float as3 = lif_step(curb[i], v, av);
        __builtin_nontemporal_store(as3 * 0.25f, &op[(size_t)i * BH]);
      }
      #pragma unroll
      for (int i = 0; i < 8; ++i) curb[i] = nxtb[i];
      p += 8 * BH; op += 8 * BH;
    }
    #pragma unroll
    for (int i = 0; i < 8; ++i) {    // tail group, already in registers
      const float as3 = lif_step(curb[i], v, av);
      __builtin_nontemporal_store(as3 * 0.25f, &op[(size_t)i * BH]);
    }
  } else {
    for (int t = 0; t < tc; ++t) {
      const float as3 = lif_step(p[0], v, av);
      *op = as3 * 0.25f;
      p += BH; op += BH;
    }
  }

  if (last) {
    #pragma unroll
    for (int l = 0; l < 4; ++l) vstate[(size_t)l * BH + idx] = av[l];
  } else {
    #pragma unroll
    for (int l = 0; l < 4; ++l) vstate[(size_t)l * BH + idx] = v[l];
  }
}

extern "C" void kernel_launch(void* const* d_in, const int* in_sizes, int n_in,
                              void* d_out, int out_size, void* d_ws, size_t ws_size,
                              hipStream_t stream) {
  const float* x = (const float*)d_in[0];   // [128,512,512] fp32
  const float* W = (const float*)d_in[1];   // [512,512] fp32
  const float* b = (const float*)d_in[2];   // [512] fp32
  float* out    = (float*)d_out;            // [128,512,512] avg spikes (fp32)
  float* states = out + (size_t)TT * BH;    // [4,512,512] final avg_v; also chunk-carry v

  int tc = TT;                              // xp chunk: tc MiB of ws
  while (tc > 1 && (size_t)tc * BH * 4ull > ws_size) tc >>= 1;
  float* xp = (float*)d_ws;
  const int nc = TT / tc;

  for (int c = 0; c < nc; ++c) {
    hipLaunchKernelGGL(gemm_f32, dim3(HID / 256, tc * BSZ / 32), dim3(256), 0, stream,
                       x + (size_t)c * tc * BH, W, b, xp);
    hipLaunchKernelGGL(lif_scan, dim3(BH / 256), dim3(256), 0, stream,
                       xp, out + (size_t)c * tc * BH, states,
                       tc, c == 0 ? 1 : 0, c == nc - 1 ? 1 : 0);
  }
}